// Round 10
// baseline (353.223 us; speedup 1.0000x reference)
//
#include <hip/hip_runtime.h>

// GCN: 2x GCNConv(+self-loops, sym-norm) + ReLU, then Linear(64->1).
// N=100000 nodes, E=1600000 edges, IN=128, HID=64, OUT=1.
//
//  - agg: L2-miss/latency bound (FETCH 86MB > working set -> L3-served),
//    ~47us x2; heavily tuned, kept (now with per-edge dq fma, ~free).
//  - R2: GEMMs on MFMA 16x16x32 bf16, hi/lo split precision (absmax held).
//  - R3 FAILED: grid.sync() coop fusion. R4/R5 FAILED: LDS-sort scatter.
//  - R7 FAILED: direct CSR random 4B scatters -> 16x write-allocate (107MB).
//    LESSON: scatter targets must stay window-local (L2).
//  - R8 WIN (257us): slack-bucket sort, 7 dispatches.
//  - R9: dq-scaling moved GEMM-epilogue -> agg (add becomes fma, same VALU):
//    gemm1 loses its CSR dependency -> FUSED with scatter (mega1, one
//    dispatch, co-resident -> true overlap of MFMA-bound gemm with
//    memory-bound scatter). Scatter now non-atomic per-(bucket,block)
//    ghist+subruns (64 blocks, CAP 128) -> NO memset, no global atomics.
//    GEMMs self-convert W fp32->hi/lo (W-prep buffers deleted).
//    Dispatches 7 -> 5. slack unions with h1b (ws ~33MB, same as R8).
//  - R10: R9 bench was an infra failure (container died twice, no compile/
//    pytest output — same signature as R4 which passed on resubmit).
//    Audited: uniform barriers, LDS 35KB, SCAP 8-sigma, aligned LDS rows,
//    ws fits. Resubmitted unchanged.

#define IN_DIM 128
#define HID 64
#define NSB 64        // scatter blocks
#define SCAP 128      // per-(bucket,block) subrun capacity (Poisson(64) mean)
#define MAXNC 512     // max coarse buckets (N <= 131072)

typedef unsigned int uint;
typedef unsigned short ushort;
typedef __attribute__((ext_vector_type(8))) short short8;   // 8 bf16 (4 VGPR)
typedef __attribute__((ext_vector_type(4))) float f32x4;

__device__ inline uint pack_bf16x2(float a, float b) {
    uint ua = __builtin_bit_cast(uint, a);
    uint ub = __builtin_bit_cast(uint, b);
    ua += 0x7fffu + ((ua >> 16) & 1u);   // RNE
    ub += 0x7fffu + ((ub >> 16) & 1u);
    return (ua >> 16) | (ub & 0xffff0000u);
}
__device__ inline float bf_lo(uint g) { return __builtin_bit_cast(float, g << 16); }
__device__ inline float bf_hi(uint g) { return __builtin_bit_cast(float, g & 0xffff0000u); }
__device__ inline uint rne_hi_bits(float a) {   // bf16(a) as fp32 bit pattern
    uint u = __builtin_bit_cast(uint, a);
    return (u + 0x7fffu + ((u >> 16) & 1u)) & 0xffff0000u;
}
__device__ inline float bitf(uint u) { return __builtin_bit_cast(float, u); }

// ---------------- MFMA GEMM body: 128 nodes x 64 cols, BK=32, self-converting W ----------------
// SPLIT=true : X fp32 [n][K], 3 terms (xh@wh + xh@wl + xl@wh)  ~= fp32 exact
// SPLIT=false: X bf16-packed, 2 terms (x@wh + x@wl) = fp32 exact
// W is ORIGINAL fp32 [K][64]; converted to hi/lo bf16 in-kernel per chunk.
// Output Tsb is UNSCALED (dq applied in agg). LDS rows padded to 80B.
template <int K, bool SPLIT>
__device__ __forceinline__ void gemm_body(int bid, const void* __restrict__ Xv,
                                          const float* __restrict__ Wf,
                                          uint* __restrict__ Tsb, int n) {
    __shared__ ushort XH[128 * 40];
    __shared__ ushort WH[64 * 40];
    __shared__ ushort WL[64 * 40];
    __shared__ ushort XL[SPLIT ? 128 * 40 : 64];

    const int tid = threadIdx.x;
    const int m0  = bid * 128;
    const float* Xf = (const float*)Xv;
    const char*  Xb = (const char*)Xv;

    // W geometry: c = tid&63, rows k0..k0+7 of the 32-row chunk
    const int wc_ = tid & 63, wk0 = (tid >> 6) * 8;

    // X chunk-load geometry
    constexpr int NL = SPLIT ? 4 : 2;
    int xr[NL], xk[NL];
#pragma unroll
    for (int i = 0; i < NL; ++i) {
        int f = tid + i * 256;
        if (SPLIT) { xr[i] = f >> 3; xk[i] = f & 7; }   // float4 per 4 k
        else       { xr[i] = f >> 2; xk[i] = f & 3; }   // uint4  per 8 k
    }

    const float4 z4 = make_float4(0.f, 0.f, 0.f, 0.f);
    const uint4  zu = make_uint4(0u, 0u, 0u, 0u);
    float4 gx[NL];
    uint4  gxb[NL];
    float  gw[8];
#pragma unroll
    for (int i = 0; i < NL; ++i) {
        int row = m0 + xr[i];
        if (SPLIT) gx[i]  = (row < n) ? *(const float4*)(Xf + (size_t)row * K + 4 * xk[i]) : z4;
        else       gxb[i] = (row < n) ? *(const uint4*)(Xb + (size_t)row * (K * 2) + xk[i] * 16) : zu;
    }
#pragma unroll
    for (int j = 0; j < 8; ++j) gw[j] = Wf[(size_t)(wk0 + j) * 64 + wc_];

    f32x4 acc[2][4] = {};
    const int l   = tid & 63, wv = tid >> 6;
    const int lr  = l & 15;
    const int kob = (l >> 4) * 16;   // byte offset of this lane's 8 bf16 within a row

    for (int kc = 0;;) {
        // ---- stage current chunk into LDS ----
        if (SPLIT) {
#pragma unroll
            for (int i = 0; i < NL; ++i) {
                float a = gx[i].x, b = gx[i].y, c = gx[i].z, d = gx[i].w;
                uint rha = rne_hi_bits(a), rhb = rne_hi_bits(b);
                uint rhc = rne_hi_bits(c), rhd = rne_hi_bits(d);
                uint2 hh, ll;
                hh.x = (rha >> 16) | (rhb & 0xffff0000u);
                hh.y = (rhc >> 16) | (rhd & 0xffff0000u);
                ll.x = pack_bf16x2(a - bitf(rha), b - bitf(rhb));
                ll.y = pack_bf16x2(c - bitf(rhc), d - bitf(rhd));
                *(uint2*)((char*)XH + xr[i] * 80 + xk[i] * 8) = hh;
                *(uint2*)((char*)XL + xr[i] * 80 + xk[i] * 8) = ll;
            }
        } else {
#pragma unroll
            for (int i = 0; i < NL; ++i)
                *(uint4*)((char*)XH + xr[i] * 80 + xk[i] * 16) = gxb[i];
        }
        // W: convert 8 fp32 -> hi/lo bf16 rows of this chunk
#pragma unroll
        for (int j = 0; j < 8; j += 2) {
            uint h0 = rne_hi_bits(gw[j]), h1 = rne_hi_bits(gw[j + 1]);
            uint hp = (h0 >> 16) | (h1 & 0xffff0000u);
            uint lp = pack_bf16x2(gw[j] - bitf(h0), gw[j + 1] - bitf(h1));
            *(uint*)((char*)WH + wc_ * 80 + (wk0 + j) * 2) = hp;
            *(uint*)((char*)WL + wc_ * 80 + (wk0 + j) * 2) = lp;
        }
        __syncthreads();

        kc += 32;
        const bool more = kc < K;
        if (more) {   // prefetch next chunk while MFMA consumes LDS
#pragma unroll
            for (int i = 0; i < NL; ++i) {
                int row = m0 + xr[i];
                if (SPLIT) gx[i]  = (row < n) ? *(const float4*)(Xf + (size_t)row * K + kc + 4 * xk[i]) : z4;
                else       gxb[i] = (row < n) ? *(const uint4*)(Xb + (size_t)row * (K * 2) + kc * 2 + xk[i] * 16) : zu;
            }
#pragma unroll
            for (int j = 0; j < 8; ++j) gw[j] = Wf[(size_t)(kc + wk0 + j) * 64 + wc_];
        }

        // ---- MFMA phase ----
        short8 xh0 = *(const short8*)((const char*)XH + (wv * 32 + 0 + lr) * 80 + kob);
        short8 xh1 = *(const short8*)((const char*)XH + (wv * 32 + 16 + lr) * 80 + kob);
        short8 xl0, xl1;
        if (SPLIT) {
            xl0 = *(const short8*)((const char*)XL + (wv * 32 + 0 + lr) * 80 + kob);
            xl1 = *(const short8*)((const char*)XL + (wv * 32 + 16 + lr) * 80 + kob);
        }
#pragma unroll
        for (int nn = 0; nn < 4; ++nn) {
            short8 wh = *(const short8*)((const char*)WH + (nn * 16 + lr) * 80 + kob);
            short8 wl = *(const short8*)((const char*)WL + (nn * 16 + lr) * 80 + kob);
            acc[0][nn] = __builtin_amdgcn_mfma_f32_16x16x32_bf16(wh, xh0, acc[0][nn], 0, 0, 0);
            acc[1][nn] = __builtin_amdgcn_mfma_f32_16x16x32_bf16(wh, xh1, acc[1][nn], 0, 0, 0);
            acc[0][nn] = __builtin_amdgcn_mfma_f32_16x16x32_bf16(wl, xh0, acc[0][nn], 0, 0, 0);
            acc[1][nn] = __builtin_amdgcn_mfma_f32_16x16x32_bf16(wl, xh1, acc[1][nn], 0, 0, 0);
            if (SPLIT) {
                acc[0][nn] = __builtin_amdgcn_mfma_f32_16x16x32_bf16(wh, xl0, acc[0][nn], 0, 0, 0);
                acc[1][nn] = __builtin_amdgcn_mfma_f32_16x16x32_bf16(wh, xl1, acc[1][nn], 0, 0, 0);
            }
        }
        if (!more) break;
        __syncthreads();
    }

    // ---- epilogue: pack bf16 (UNSCALED), store 8B/lane ----
#pragma unroll
    for (int m = 0; m < 2; ++m) {
        int node = m0 + wv * 32 + m * 16 + lr;
        if (node < n) {
#pragma unroll
            for (int nn = 0; nn < 4; ++nn) {
                f32x4 a = acc[m][nn];
                uint2 pk;
                pk.x = pack_bf16x2(a[0], a[1]);
                pk.y = pack_bf16x2(a[2], a[3]);
                *(uint2*)((char*)Tsb + (size_t)node * 128 + nn * 32 + (l >> 4) * 8) = pk;
            }
        }
    }
}

// ---------------- scatter body: non-atomic ghist + per-(bucket,block) subruns ----------------
__device__ __forceinline__ void scatter_body(int blk, const int* __restrict__ src,
                                             const int* __restrict__ dst,
                                             int* __restrict__ ghist,
                                             uint* __restrict__ slack,
                                             int E, int NC, int chunk) {
    __shared__ int h[MAXNC], cur[MAXNC];
    int t = threadIdx.x;
    for (int i = t; i < NC; i += 256) h[i] = 0;
    __syncthreads();
    int s = blk * chunk, e = min(E, s + chunk);
    for (int i = s + t; i < e; i += 256) atomicAdd(&h[dst[i] >> 8], 1);
    __syncthreads();
    for (int i = t; i < NC; i += 256) {   // full overwrite: no init needed
        ghist[i * NSB + blk] = h[i];
        cur[i] = 0;
    }
    __syncthreads();
    for (int i = s + t; i < e; i += 256) {
        int d = dst[i], b = d >> 8;
        int p = atomicAdd(&cur[b], 1);    // LDS slot within (bucket, block)
        slack[((size_t)b * NSB + blk) * SCAP + p] = ((uint)src[i] << 8) | (uint)(d & 255);
    }
}

// ---------------- mega1: gemm layer-1 (blocks < gemmN) + scatter (rest) ----------------
__global__ __launch_bounds__(256) void mega1(const float* __restrict__ x,
                                             const float* __restrict__ W1,
                                             const int* __restrict__ src,
                                             const int* __restrict__ dst,
                                             int* __restrict__ ghist,
                                             uint* __restrict__ slack,
                                             uint* __restrict__ Tsb,
                                             int n, int E, int NC, int chunk,
                                             int gemmN) {
    if ((int)blockIdx.x < gemmN)
        gemm_body<IN_DIM, true>(blockIdx.x, x, W1, Tsb, n);
    else
        scatter_body(blockIdx.x - gemmN, src, dst, ghist, slack, E, NC, chunk);
}

// ---------------- gemm layer-2 (standalone) ----------------
__global__ __launch_bounds__(256) void gemm2k(const uint* __restrict__ h1b,
                                              const float* __restrict__ W2,
                                              uint* __restrict__ Tsb, int n) {
    gemm_body<HID, false>(blockIdx.x, h1b, W2, Tsb, n);
}

// ---------------- build_csr2: bases from ghist prefix; place col from subruns ----------------
__global__ __launch_bounds__(256) void build_csr2(const int* __restrict__ ghist,
                                                  const uint* __restrict__ slack,
                                                  int* __restrict__ row_off,
                                                  float* __restrict__ disqrt,
                                                  int* __restrict__ col,
                                                  int NC, int N) {
    __shared__ int red[4], ws[4], wsoff[4];
    __shared__ int h[256], cur[256], sub[NSB];
    int b = blockIdx.x, t = threadIdx.x;
    // base = sum of all ghist cells with bucket < b  (flat range [0, b*NSB))
    int part = 0;
    for (int i = t; i < b * NSB; i += 256) part += ghist[i];
#pragma unroll
    for (int o = 32; o; o >>= 1) part += __shfl_down(part, o, 64);
    if ((t & 63) == 0) red[t >> 6] = part;
    if (t < NSB) sub[t] = ghist[b * NSB + t];
    h[t] = 0;
    __syncthreads();
    const int base = red[0] + red[1] + red[2] + red[3];
    // hist pass over this bucket's subruns (4 threads per subrun)
    {
        int sr = t & (NSB - 1), li = t >> 6;
        int c = sub[sr];
        const uint* bp = slack + ((size_t)b * NSB + sr) * SCAP;
        for (int j = li; j < c; j += 4) atomicAdd(&h[bp[j] & 255u], 1);
    }
    __syncthreads();
    int deg = h[t];
    int incl = deg;
#pragma unroll
    for (int o = 1; o < 64; o <<= 1) {
        int u = __shfl_up(incl, o, 64);
        if ((t & 63) >= o) incl += u;
    }
    if ((t & 63) == 63) ws[t >> 6] = incl;
    __syncthreads();
    if (t == 0) {
        int run = 0;
#pragma unroll
        for (int i = 0; i < 4; ++i) { wsoff[i] = run; run += ws[i]; }
    }
    __syncthreads();
    int excl = wsoff[t >> 6] + incl - deg;
    cur[t] = base + excl;
    int node = (b << 8) + t;
    if (node < N) {
        row_off[node] = base + excl;
        disqrt[node]  = rsqrtf((float)(deg + 1));  // +1 self-loop
    }
    if (b == NC - 1 && t == 0) row_off[N] = base + wsoff[3] + ws[3];
    __syncthreads();
    // place pass
    {
        int sr = t & (NSB - 1), li = t >> 6;
        int c = sub[sr];
        const uint* bp = slack + ((size_t)b * NSB + sr) * SCAP;
        for (int j = li; j < c; j += 4) {
            uint p = bp[j];
            int pos = atomicAdd(&cur[p & 255u], 1);   // LDS atomic, global pos
            col[pos] = (int)(p >> 8);                 // 16KB window, L2-local
        }
    }
}

// ---------------- aggregation: wave per node, eighth-wave per edge ----------------
// R9: Ts is UNSCALED; per-edge dq_src applied via fma (same VALU count as add).
template <bool FUSE_FC>
__global__ __launch_bounds__(256) void agg_kernel(const uint* __restrict__ Tsb,
                                                  const int* __restrict__ row_off,
                                                  const int* __restrict__ col,
                                                  const float* __restrict__ disqrt,
                                                  const float* __restrict__ bias,
                                                  const float* __restrict__ wfc,
                                                  const float* __restrict__ bfc,
                                                  uint* __restrict__ outb,
                                                  float* __restrict__ outf,
                                                  int node0, int nhi) {
    int node = node0 + blockIdx.x * 4 + (threadIdx.x >> 6);
    if (node >= nhi) return;
    int lane = threadIdx.x & 63;
    int o = lane >> 3;      // octant id: edge slot within group of 8
    int p = lane & 7;       // uint4 index (features 8p..8p+7)
    float dqn = disqrt[node];
    float acc[8] = {};
    if (o == 0) {   // self-loop: dq_s = dq_d = dqn
        uint4 g = *(const uint4*)(Tsb + (size_t)node * 32 + 4 * p);
        acc[0] = dqn * bf_lo(g.x); acc[1] = dqn * bf_hi(g.x);
        acc[2] = dqn * bf_lo(g.y); acc[3] = dqn * bf_hi(g.y);
        acc[4] = dqn * bf_lo(g.z); acc[5] = dqn * bf_hi(g.z);
        acc[6] = dqn * bf_lo(g.w); acc[7] = dqn * bf_hi(g.w);
    }
    int beg = __builtin_amdgcn_readfirstlane(row_off[node]);
    int end = __builtin_amdgcn_readfirstlane(row_off[node + 1]);
    for (int batch = beg; batch < end; batch += 64) {
        int bn = min(64, end - batch);
        int cv = 0;
        float dqv = 0.f;
        if (batch + lane < end) {
            cv  = col[batch + lane];    // coalesced
            dqv = disqrt[cv];           // L2-resident 400KB gather
        }
        int j = 0;
        for (; j + 16 <= bn; j += 16) {
            int   s0 = __shfl(cv,  j + o, 64);
            float q0 = __shfl(dqv, j + o, 64);
            int   s1 = __shfl(cv,  j + 8 + o, 64);
            float q1 = __shfl(dqv, j + 8 + o, 64);
            uint4 g0 = *(const uint4*)(Tsb + (size_t)s0 * 32 + 4 * p);
            uint4 g1 = *(const uint4*)(Tsb + (size_t)s1 * 32 + 4 * p);
            acc[0] += q0 * bf_lo(g0.x); acc[1] += q0 * bf_hi(g0.x);
            acc[2] += q0 * bf_lo(g0.y); acc[3] += q0 * bf_hi(g0.y);
            acc[4] += q0 * bf_lo(g0.z); acc[5] += q0 * bf_hi(g0.z);
            acc[6] += q0 * bf_lo(g0.w); acc[7] += q0 * bf_hi(g0.w);
            acc[0] += q1 * bf_lo(g1.x); acc[1] += q1 * bf_hi(g1.x);
            acc[2] += q1 * bf_lo(g1.y); acc[3] += q1 * bf_hi(g1.y);
            acc[4] += q1 * bf_lo(g1.z); acc[5] += q1 * bf_hi(g1.z);
            acc[6] += q1 * bf_lo(g1.w); acc[7] += q1 * bf_hi(g1.w);
        }
        for (; j < bn; j += 8) {
            int idx = j + o;
            int   s = __shfl(cv,  idx & 63, 64);
            float q = __shfl(dqv, idx & 63, 64);
            uint4 g = *(const uint4*)(Tsb + (size_t)s * 32 + 4 * p);
            if (idx < bn) {
                acc[0] += q * bf_lo(g.x); acc[1] += q * bf_hi(g.x);
                acc[2] += q * bf_lo(g.y); acc[3] += q * bf_hi(g.y);
                acc[4] += q * bf_lo(g.z); acc[5] += q * bf_hi(g.z);
                acc[6] += q * bf_lo(g.w); acc[7] += q * bf_hi(g.w);
            }
        }
    }
#pragma unroll
    for (int k = 0; k < 8; ++k) {
        acc[k] += __shfl_xor(acc[k], 8, 64);
        acc[k] += __shfl_xor(acc[k], 16, 64);
        acc[k] += __shfl_xor(acc[k], 32, 64);
    }
    float4 bv0 = *(const float4*)(bias + 8 * p);
    float4 bv1 = *(const float4*)(bias + 8 * p + 4);
    float r[8];
    r[0] = fmaxf(acc[0] * dqn + bv0.x, 0.f);
    r[1] = fmaxf(acc[1] * dqn + bv0.y, 0.f);
    r[2] = fmaxf(acc[2] * dqn + bv0.z, 0.f);
    r[3] = fmaxf(acc[3] * dqn + bv0.w, 0.f);
    r[4] = fmaxf(acc[4] * dqn + bv1.x, 0.f);
    r[5] = fmaxf(acc[5] * dqn + bv1.y, 0.f);
    r[6] = fmaxf(acc[6] * dqn + bv1.z, 0.f);
    r[7] = fmaxf(acc[7] * dqn + bv1.w, 0.f);
    if (!FUSE_FC) {
        if (o == 0) {   // pack to bf16 for next layer
            uint4 pk;
            pk.x = pack_bf16x2(r[0], r[1]);
            pk.y = pack_bf16x2(r[2], r[3]);
            pk.z = pack_bf16x2(r[4], r[5]);
            pk.w = pack_bf16x2(r[6], r[7]);
            *(uint4*)(outb + (size_t)node * 32 + 4 * p) = pk;
        }
    } else {
        float4 wv0 = *(const float4*)(wfc + 8 * p);
        float4 wv1 = *(const float4*)(wfc + 8 * p + 4);
        float v = r[0] * wv0.x + r[1] * wv0.y + r[2] * wv0.z + r[3] * wv0.w +
                  r[4] * wv1.x + r[5] * wv1.y + r[6] * wv1.z + r[7] * wv1.w;
        v += __shfl_down(v, 4, 64);
        v += __shfl_down(v, 2, 64);
        v += __shfl_down(v, 1, 64);
        if (lane == 0) outf[node] = v + bfc[0];
    }
}

extern "C" void kernel_launch(void* const* d_in, const int* in_sizes, int n_in,
                              void* d_out, int out_size, void* d_ws, size_t ws_size,
                              hipStream_t stream) {
    const float* x   = (const float*)d_in[0];
    const int*   ei  = (const int*)d_in[1];
    const float* W1  = (const float*)d_in[2];
    const float* b1  = (const float*)d_in[3];
    const float* W2  = (const float*)d_in[4];
    const float* b2  = (const float*)d_in[5];
    const float* Wfc = (const float*)d_in[6];
    const float* bfc = (const float*)d_in[7];
    float* out = (float*)d_out;

    const int N = in_sizes[0] / IN_DIM;
    const int E = in_sizes[1] / 2;
    const int* src = ei;
    const int* dst = ei + E;
    const int NC    = (N + 255) >> 8;        // 256-node buckets
    const int chunk = (E + NSB - 1) / NSB;   // edges per scatter block
    const int gemmN = (N + 127) / 128;       // gemm layer-1 blocks

    // ---- workspace carve-up (256B aligned) ----
    char* w = (char*)d_ws;
    auto alloc = [&](size_t bytes) {
        void* p = (void*)w;
        w += (bytes + 255) & ~(size_t)255;
        return p;
    };
    int*   row_off = (int*)alloc((size_t)(N + 1) * 4);
    float* disqrt  = (float*)alloc((size_t)N * 4);
    int*   ghist   = (int*)alloc((size_t)MAXNC * NSB * 4);
    int*   col     = (int*)alloc((size_t)E * 4);
    uint*  Tsb     = (uint*)alloc((size_t)N * HID * 2);          // Ts (unscaled bf16)
    // slack (NC*NSB*SCAP*4 = 12.8MB) unions with h1b (N*128B = 12.8MB):
    // slack dead after build_csr2, h1b written by agg1 (later). Safe.
    size_t slackB = (size_t)NC * NSB * SCAP * 4;
    size_t h1B    = (size_t)N * HID * 2;
    void*  scr    = alloc(slackB > h1B ? slackB : h1B);
    uint*  slack  = (uint*)scr;
    uint*  h1b    = (uint*)scr;

    // ---- dispatch 1: mega1 = gemm layer-1 (unscaled) + bucket scatter ----
    mega1<<<gemmN + NSB, 256, 0, stream>>>(x, W1, src, dst, ghist, slack,
                                           Tsb, N, E, NC, chunk, gemmN);

    // ---- dispatch 2: CSR finalize (row_off, disqrt, col) ----
    build_csr2<<<NC, 256, 0, stream>>>(ghist, slack, row_off, disqrt, col, NC, N);

    // ---- dispatch 3: layer-1 aggregation (dq-aware) -> h1 bf16 ----
    agg_kernel<false><<<(N + 3) / 4, 256, 0, stream>>>(Tsb, row_off, col, disqrt,
                                                       b1, nullptr, nullptr,
                                                       h1b, nullptr, 0, N);

    // ---- dispatch 4: gemm layer-2 (unscaled) ----
    gemm2k<<<gemmN, 256, 0, stream>>>(h1b, W2, Tsb, N);

    // ---- dispatch 5: layer-2 aggregation + fused fc ----
    agg_kernel<true><<<(N + 3) / 4, 256, 0, stream>>>(Tsb, row_off, col, disqrt,
                                                      b2, Wfc, bfc,
                                                      nullptr, out, 0, N);
}

// Round 11
// 255.686 us; speedup vs baseline: 1.3815x; 1.3815x over previous
//
#include <hip/hip_runtime.h>

// GCN: 2x GCNConv(+self-loops, sym-norm) + ReLU, then Linear(64->1).
// N=100000 nodes, E=1600000 edges, IN=128, HID=64, OUT=1.
//
//  - agg near floor: 86MB HBM random 128B gathers, ~47us x2. FROZEN.
//  - R2: GEMMs on MFMA 16x16x32 bf16, hi/lo split precision (absmax held).
//  - R3 FAILED: grid.sync() coop fusion 264us (cross-XCD barrier fences).
//  - R4/R5 FAILED: LDS counting-sort scatter cost > coalescing gain.
//  - R7 FAILED (mechanism found): direct CSR build's random 4B scatters over
//    6.4MB col -> 107MB WRITE_SIZE (16x write-allocate amplification).
//    LESSON: scatter targets must stay window-local (L2).
//  - R8 WIN (257us): slack-bucket sort, 7 dispatches. THIS KERNEL.
//  - R9/R10 FAILED: mega1 (gemm1+scatter fused, 64 fat scatter blocks)
//    -> straggler tail at 1-6% occupancy, 353us. LESSON: fusing unlike
//    kernels loses to separate dispatches (load-imbalance tail + LDS union).
//  - R11: reverted to R8 exactly — best measured, all components proven.
//  - Ts/h1 stored bf16 (packed bf16x2); fp32 accumulate everywhere.

#define IN_DIM 128
#define HID 64
#define B1 256        // level-1 scatter blocks (chunks)
#define MAXNC 512     // max coarse buckets (N <= 131072)
#define BCAP 8192     // bucket slack capacity (mean 4092, ~32 sigma margin)

typedef unsigned int uint;
typedef unsigned short ushort;
typedef __attribute__((ext_vector_type(8))) short short8;   // 8 bf16 (4 VGPR)
typedef __attribute__((ext_vector_type(4))) float f32x4;

__device__ inline uint pack_bf16x2(float a, float b) {
    uint ua = __builtin_bit_cast(uint, a);
    uint ub = __builtin_bit_cast(uint, b);
    ua += 0x7fffu + ((ua >> 16) & 1u);   // RNE
    ub += 0x7fffu + ((ub >> 16) & 1u);
    return (ua >> 16) | (ub & 0xffff0000u);
}
__device__ inline float bf_lo(uint g) { return __builtin_bit_cast(float, g << 16); }
__device__ inline float bf_hi(uint g) { return __builtin_bit_cast(float, g & 0xffff0000u); }
__device__ inline uint rne_hi_bits(float a) {   // bf16(a) as fp32 bit pattern
    uint u = __builtin_bit_cast(uint, a);
    return (u + 0x7fffu + ((u >> 16) & 1u)) & 0xffff0000u;
}
__device__ inline float bitf(uint u) { return __builtin_bit_cast(float, u); }

// ---------------- level-1 scatter into slack buckets + W prep ----------------
// Blocks [0,B1): per-chunk LDS hist -> global run reservation -> run writes.
// Block B1: W1 hi/lo transpose prep.  Block B1+1: W2 prep.
__global__ __launch_bounds__(512) void scatter_bkt(
        const int* __restrict__ src, const int* __restrict__ dst,
        int* __restrict__ bktcnt, uint* __restrict__ slack,
        int E, int NC, int chunk,
        const float* __restrict__ W1f, const float* __restrict__ W2f,
        ushort* __restrict__ w1h, ushort* __restrict__ w1l,
        ushort* __restrict__ w2h, ushort* __restrict__ w2l) {
    int t = threadIdx.x, blk = blockIdx.x;
    if (blk < B1) {
        __shared__ int h[MAXNC], cur[MAXNC];
        for (int i = t; i < NC; i += 512) h[i] = 0;
        __syncthreads();
        int s = blk * chunk, e = min(E, s + chunk);
        for (int i = s + t; i < e; i += 512) atomicAdd(&h[dst[i] >> 8], 1);
        __syncthreads();
        for (int i = t; i < NC; i += 512)
            cur[i] = h[i] ? atomicAdd(&bktcnt[i], h[i]) : 0;   // reserve run
        __syncthreads();
        for (int i = s + t; i < e; i += 512) {
            int d = dst[i], b = d >> 8;
            int p = atomicAdd(&cur[b], 1);                     // slot in bucket
            slack[(size_t)b * BCAP + p] = ((uint)src[i] << 8) | (uint)(d & 255);
        }
    } else if (blk == B1) {
        for (int i = t; i < 128 * 64; i += 512) {
            int k = i >> 6, c = i & 63;
            float v = W1f[i];
            uint rh = rne_hi_bits(v);
            w1h[c * 128 + k] = (ushort)(rh >> 16);
            w1l[c * 128 + k] = (ushort)(rne_hi_bits(v - bitf(rh)) >> 16);
        }
    } else {
        for (int i = t; i < 64 * 64; i += 512) {
            int k = i >> 6, c = i & 63;
            float v = W2f[i];
            uint rh = rne_hi_bits(v);
            w2h[c * 64 + k] = (ushort)(rh >> 16);
            w2l[c * 64 + k] = (ushort)(rne_hi_bits(v - bitf(rh)) >> 16);
        }
    }
}

// ---------------- level-2: per-bucket CSR build (256-node buckets) ----------------
// base_g derived by redundantly summing bktcnt[0..b) (391 ints, L2-hot).
__global__ __launch_bounds__(256) void build_csr2(const int* __restrict__ bktcnt,
                                                  const uint* __restrict__ slack,
                                                  int* __restrict__ row_off,
                                                  float* __restrict__ disqrt,
                                                  int* __restrict__ col,
                                                  int NC, int N) {
    __shared__ int red[4], ws[4], wsoff[4];
    __shared__ int h[256], cur[256];
    int b = blockIdx.x, t = threadIdx.x;
    // partial sums of bktcnt[0..b)
    int part = 0;
    for (int i = t; i < b; i += 256) part += bktcnt[i];
#pragma unroll
    for (int o = 32; o; o >>= 1) part += __shfl_down(part, o, 64);
    if ((t & 63) == 0) red[t >> 6] = part;
    h[t] = 0;
    __syncthreads();
    const int base = red[0] + red[1] + red[2] + red[3];
    const int cnt  = bktcnt[b];
    const uint* bp = slack + (size_t)b * BCAP;
    for (int i = t; i < cnt; i += 256)
        atomicAdd(&h[bp[i] & 255u], 1);
    __syncthreads();
    int deg = h[t];
    int incl = deg;
#pragma unroll
    for (int o = 1; o < 64; o <<= 1) {
        int u = __shfl_up(incl, o, 64);
        if ((t & 63) >= o) incl += u;
    }
    if ((t & 63) == 63) ws[t >> 6] = incl;
    __syncthreads();
    if (t == 0) {
        int run = 0;
#pragma unroll
        for (int i = 0; i < 4; ++i) { wsoff[i] = run; run += ws[i]; }
    }
    __syncthreads();
    int excl = wsoff[t >> 6] + incl - deg;
    cur[t] = base + excl;
    int node = (b << 8) + t;
    if (node < N) {
        row_off[node] = base + excl;
        disqrt[node]  = rsqrtf((float)(deg + 1));  // +1 self-loop
    }
    if (b == NC - 1 && t == 0) row_off[N] = base + cnt;
    __syncthreads();
    for (int i = t; i < cnt; i += 256) {
        uint p = bp[i];
        int pos = atomicAdd(&cur[p & 255u], 1);   // LDS atomic, global pos
        col[pos] = (int)(p >> 8);                 // 16KB window, L2-local
    }
}

// ---------------- MFMA GEMM: 128 nodes x 64 cols per block, BK=32 chunks ----------------
// SPLIT=true : X fp32 [n][K], 3 terms (xh@wh + xh@wl + xl@wh)  ~= fp32 exact
// SPLIT=false: X bf16-packed [n][K/2 uints], 2 terms (x@wh + x@wl) = fp32 exact
// Swapped operands: A = W^T frag (M=out col), B = X frag (N=node) so the
// epilogue writes 8B/lane contiguous. LDS rows padded to 80B.
template <int K, bool SPLIT>
__global__ __launch_bounds__(256) void gemm_mfma(const void* __restrict__ Xv,
                                                 const ushort* __restrict__ WHt,
                                                 const ushort* __restrict__ WLt,
                                                 const float* __restrict__ disqrt,
                                                 uint* __restrict__ Tsb, int n) {
    __shared__ ushort XH[128 * 40];
    __shared__ ushort WH[64 * 40];
    __shared__ ushort WL[64 * 40];
    __shared__ ushort XL[SPLIT ? 128 * 40 : 64];

    const int tid = threadIdx.x;
    const int m0  = blockIdx.x * 128;
    const float* Xf = (const float*)Xv;
    const char*  Xb = (const char*)Xv;

    // W chunk-load geometry: 64 cols x 4 slots of 16B
    const int wc = tid >> 2, wslot = tid & 3;
    const char* wh_g = (const char*)WHt + wc * (K * 2) + wslot * 16;
    const char* wl_g = (const char*)WLt + wc * (K * 2) + wslot * 16;

    // X chunk-load geometry
    constexpr int NL = SPLIT ? 4 : 2;
    int xr[NL], xk[NL];
#pragma unroll
    for (int i = 0; i < NL; ++i) {
        int f = tid + i * 256;
        if (SPLIT) { xr[i] = f >> 3; xk[i] = f & 7; }   // float4 per 4 k
        else       { xr[i] = f >> 2; xk[i] = f & 3; }   // uint4  per 8 k
    }

    const float4 z4 = make_float4(0.f, 0.f, 0.f, 0.f);
    const uint4  zu = make_uint4(0u, 0u, 0u, 0u);
    float4 gx[NL];
    uint4  gxb[NL];
    uint4  gwh, gwl;
#pragma unroll
    for (int i = 0; i < NL; ++i) {
        int row = m0 + xr[i];
        if (SPLIT) gx[i]  = (row < n) ? *(const float4*)(Xf + (size_t)row * K + 4 * xk[i]) : z4;
        else       gxb[i] = (row < n) ? *(const uint4*)(Xb + (size_t)row * (K * 2) + xk[i] * 16) : zu;
    }
    gwh = *(const uint4*)wh_g;
    gwl = *(const uint4*)wl_g;

    f32x4 acc[2][4] = {};
    const int l   = tid & 63, wv = tid >> 6;
    const int lr  = l & 15;
    const int kob = (l >> 4) * 16;   // byte offset of this lane's 8 bf16 within a row

    for (int kc = 0;;) {
        // ---- stage current chunk into LDS ----
        if (SPLIT) {
#pragma unroll
            for (int i = 0; i < NL; ++i) {
                float a = gx[i].x, b = gx[i].y, c = gx[i].z, d = gx[i].w;
                uint rha = rne_hi_bits(a), rhb = rne_hi_bits(b);
                uint rhc = rne_hi_bits(c), rhd = rne_hi_bits(d);
                uint2 hh, ll;
                hh.x = (rha >> 16) | (rhb & 0xffff0000u);
                hh.y = (rhc >> 16) | (rhd & 0xffff0000u);
                ll.x = pack_bf16x2(a - bitf(rha), b - bitf(rhb));
                ll.y = pack_bf16x2(c - bitf(rhc), d - bitf(rhd));
                *(uint2*)((char*)XH + xr[i] * 80 + xk[i] * 8) = hh;
                *(uint2*)((char*)XL + xr[i] * 80 + xk[i] * 8) = ll;
            }
        } else {
#pragma unroll
            for (int i = 0; i < NL; ++i)
                *(uint4*)((char*)XH + xr[i] * 80 + xk[i] * 16) = gxb[i];
        }
        *(uint4*)((char*)WH + wc * 80 + wslot * 16) = gwh;
        *(uint4*)((char*)WL + wc * 80 + wslot * 16) = gwl;
        __syncthreads();

        kc += 32;
        const bool more = kc < K;
        if (more) {   // prefetch next chunk while MFMA consumes LDS
#pragma unroll
            for (int i = 0; i < NL; ++i) {
                int row = m0 + xr[i];
                if (SPLIT) gx[i]  = (row < n) ? *(const float4*)(Xf + (size_t)row * K + kc + 4 * xk[i]) : z4;
                else       gxb[i] = (row < n) ? *(const uint4*)(Xb + (size_t)row * (K * 2) + kc * 2 + xk[i] * 16) : zu;
            }
            gwh = *(const uint4*)(wh_g + kc * 2);
            gwl = *(const uint4*)(wl_g + kc * 2);
        }

        // ---- MFMA phase ----
        short8 xh0 = *(const short8*)((const char*)XH + (wv * 32 + 0 + lr) * 80 + kob);
        short8 xh1 = *(const short8*)((const char*)XH + (wv * 32 + 16 + lr) * 80 + kob);
        short8 xl0, xl1;
        if (SPLIT) {
            xl0 = *(const short8*)((const char*)XL + (wv * 32 + 0 + lr) * 80 + kob);
            xl1 = *(const short8*)((const char*)XL + (wv * 32 + 16 + lr) * 80 + kob);
        }
#pragma unroll
        for (int nn = 0; nn < 4; ++nn) {
            short8 wh = *(const short8*)((const char*)WH + (nn * 16 + lr) * 80 + kob);
            short8 wl = *(const short8*)((const char*)WL + (nn * 16 + lr) * 80 + kob);
            acc[0][nn] = __builtin_amdgcn_mfma_f32_16x16x32_bf16(wh, xh0, acc[0][nn], 0, 0, 0);
            acc[1][nn] = __builtin_amdgcn_mfma_f32_16x16x32_bf16(wh, xh1, acc[1][nn], 0, 0, 0);
            acc[0][nn] = __builtin_amdgcn_mfma_f32_16x16x32_bf16(wl, xh0, acc[0][nn], 0, 0, 0);
            acc[1][nn] = __builtin_amdgcn_mfma_f32_16x16x32_bf16(wl, xh1, acc[1][nn], 0, 0, 0);
            if (SPLIT) {
                acc[0][nn] = __builtin_amdgcn_mfma_f32_16x16x32_bf16(wh, xl0, acc[0][nn], 0, 0, 0);
                acc[1][nn] = __builtin_amdgcn_mfma_f32_16x16x32_bf16(wh, xl1, acc[1][nn], 0, 0, 0);
            }
        }
        if (!more) break;
        __syncthreads();
    }

    // ---- epilogue: scale by disqrt, pack bf16, store 8B/lane ----
#pragma unroll
    for (int m = 0; m < 2; ++m) {
        int node = m0 + wv * 32 + m * 16 + lr;
        if (node < n) {
            float dq = disqrt[node];
#pragma unroll
            for (int nn = 0; nn < 4; ++nn) {
                f32x4 a = acc[m][nn];
                uint2 pk;
                pk.x = pack_bf16x2(a[0] * dq, a[1] * dq);
                pk.y = pack_bf16x2(a[2] * dq, a[3] * dq);
                *(uint2*)((char*)Tsb + (size_t)node * 128 + nn * 32 + (l >> 4) * 8) = pk;
            }
        }
    }
}

// ---------------- aggregation: wave per node, eighth-wave per edge (FROZEN) ----------------
template <bool FUSE_FC>
__global__ __launch_bounds__(256) void agg_kernel(const uint* __restrict__ Tsb,
                                                  const int* __restrict__ row_off,
                                                  const int* __restrict__ col,
                                                  const float* __restrict__ disqrt,
                                                  const float* __restrict__ bias,
                                                  const float* __restrict__ wfc,
                                                  const float* __restrict__ bfc,
                                                  uint* __restrict__ outb,
                                                  float* __restrict__ outf,
                                                  int node0, int nhi) {
    int node = node0 + blockIdx.x * 4 + (threadIdx.x >> 6);
    if (node >= nhi) return;
    int lane = threadIdx.x & 63;
    int o = lane >> 3;      // octant id: edge slot within group of 8
    int p = lane & 7;       // uint4 index (features 8p..8p+7)
    float acc[8] = {};
    if (o == 0) {   // self-loop, octant 0 only
        uint4 g = *(const uint4*)(Tsb + (size_t)node * 32 + 4 * p);
        acc[0] = bf_lo(g.x); acc[1] = bf_hi(g.x);
        acc[2] = bf_lo(g.y); acc[3] = bf_hi(g.y);
        acc[4] = bf_lo(g.z); acc[5] = bf_hi(g.z);
        acc[6] = bf_lo(g.w); acc[7] = bf_hi(g.w);
    }
    int beg = __builtin_amdgcn_readfirstlane(row_off[node]);
    int end = __builtin_amdgcn_readfirstlane(row_off[node + 1]);
    for (int batch = beg; batch < end; batch += 64) {
        int bn = min(64, end - batch);
        int cv = 0;
        if (batch + lane < end) cv = col[batch + lane];  // ONE coalesced load
        int j = 0;
        for (; j + 16 <= bn; j += 16) {
            int s0 = __shfl(cv, j + o, 64);
            int s1 = __shfl(cv, j + 8 + o, 64);
            uint4 g0 = *(const uint4*)(Tsb + (size_t)s0 * 32 + 4 * p);
            uint4 g1 = *(const uint4*)(Tsb + (size_t)s1 * 32 + 4 * p);
            acc[0] += bf_lo(g0.x); acc[1] += bf_hi(g0.x);
            acc[2] += bf_lo(g0.y); acc[3] += bf_hi(g0.y);
            acc[4] += bf_lo(g0.z); acc[5] += bf_hi(g0.z);
            acc[6] += bf_lo(g0.w); acc[7] += bf_hi(g0.w);
            acc[0] += bf_lo(g1.x); acc[1] += bf_hi(g1.x);
            acc[2] += bf_lo(g1.y); acc[3] += bf_hi(g1.y);
            acc[4] += bf_lo(g1.z); acc[5] += bf_hi(g1.z);
            acc[6] += bf_lo(g1.w); acc[7] += bf_hi(g1.w);
        }
        for (; j < bn; j += 8) {
            int idx = j + o;
            int s = __shfl(cv, idx & 63, 64);
            uint4 g = *(const uint4*)(Tsb + (size_t)s * 32 + 4 * p);
            if (idx < bn) {
                acc[0] += bf_lo(g.x); acc[1] += bf_hi(g.x);
                acc[2] += bf_lo(g.y); acc[3] += bf_hi(g.y);
                acc[4] += bf_lo(g.z); acc[5] += bf_hi(g.z);
                acc[6] += bf_lo(g.w); acc[7] += bf_hi(g.w);
            }
        }
    }
#pragma unroll
    for (int k = 0; k < 8; ++k) {
        acc[k] += __shfl_xor(acc[k], 8, 64);
        acc[k] += __shfl_xor(acc[k], 16, 64);
        acc[k] += __shfl_xor(acc[k], 32, 64);
    }
    float dq = disqrt[node];
    float4 bv0 = *(const float4*)(bias + 8 * p);
    float4 bv1 = *(const float4*)(bias + 8 * p + 4);
    float r[8];
    r[0] = fmaxf(acc[0] * dq + bv0.x, 0.f);
    r[1] = fmaxf(acc[1] * dq + bv0.y, 0.f);
    r[2] = fmaxf(acc[2] * dq + bv0.z, 0.f);
    r[3] = fmaxf(acc[3] * dq + bv0.w, 0.f);
    r[4] = fmaxf(acc[4] * dq + bv1.x, 0.f);
    r[5] = fmaxf(acc[5] * dq + bv1.y, 0.f);
    r[6] = fmaxf(acc[6] * dq + bv1.z, 0.f);
    r[7] = fmaxf(acc[7] * dq + bv1.w, 0.f);
    if (!FUSE_FC) {
        if (o == 0) {   // pack to bf16 for next layer
            uint4 pk;
            pk.x = pack_bf16x2(r[0], r[1]);
            pk.y = pack_bf16x2(r[2], r[3]);
            pk.z = pack_bf16x2(r[4], r[5]);
            pk.w = pack_bf16x2(r[6], r[7]);
            *(uint4*)(outb + (size_t)node * 32 + 4 * p) = pk;
        }
    } else {
        float4 wv0 = *(const float4*)(wfc + 8 * p);
        float4 wv1 = *(const float4*)(wfc + 8 * p + 4);
        float v = r[0] * wv0.x + r[1] * wv0.y + r[2] * wv0.z + r[3] * wv0.w +
                  r[4] * wv1.x + r[5] * wv1.y + r[6] * wv1.z + r[7] * wv1.w;
        v += __shfl_down(v, 4, 64);
        v += __shfl_down(v, 2, 64);
        v += __shfl_down(v, 1, 64);
        if (lane == 0) outf[node] = v + bfc[0];
    }
}

extern "C" void kernel_launch(void* const* d_in, const int* in_sizes, int n_in,
                              void* d_out, int out_size, void* d_ws, size_t ws_size,
                              hipStream_t stream) {
    const float* x   = (const float*)d_in[0];
    const int*   ei  = (const int*)d_in[1];
    const float* W1  = (const float*)d_in[2];
    const float* b1  = (const float*)d_in[3];
    const float* W2  = (const float*)d_in[4];
    const float* b2  = (const float*)d_in[5];
    const float* Wfc = (const float*)d_in[6];
    const float* bfc = (const float*)d_in[7];
    float* out = (float*)d_out;

    const int N = in_sizes[0] / IN_DIM;
    const int E = in_sizes[1] / 2;
    const int* src = ei;
    const int* dst = ei + E;
    const int NC    = (N + 255) >> 8;        // 256-node buckets
    const int chunk = (E + B1 - 1) / B1;     // edges per level-1 block

    // ---- workspace carve-up (256B aligned) ----
    char* w = (char*)d_ws;
    auto alloc = [&](size_t bytes) {
        void* p = (void*)w;
        w += (bytes + 255) & ~(size_t)255;
        return p;
    };
    int*   row_off = (int*)alloc((size_t)(N + 1) * 4);
    float* disqrt  = (float*)alloc((size_t)N * 4);
    int*   bktcnt  = (int*)alloc(MAXNC * 4);
    int*   col     = (int*)alloc((size_t)E * 4);
    ushort* w1h    = (ushort*)alloc(64 * 128 * 2);   // W1^T hi bf16
    ushort* w1l    = (ushort*)alloc(64 * 128 * 2);   // W1^T lo bf16
    ushort* w2h    = (ushort*)alloc(64 * 64 * 2);    // W2^T hi bf16
    ushort* w2l    = (ushort*)alloc(64 * 64 * 2);    // W2^T lo bf16
    // scratch union: slack buckets (NC*BCAP*4) first, then Ts bf16 (N*128B)
    size_t scrA = (size_t)NC * BCAP * 4, scrB = (size_t)N * HID * 2;
    void*  scr  = alloc(scrA > scrB ? scrA : scrB);
    uint*  h1b  = (uint*)alloc((size_t)N * HID * 2);   // h1 in packed bf16
    uint*  slack = (uint*)scr;
    uint*  Tsb   = (uint*)scr;

    // ---- build CSR: slack-bucket sort (2 kernels + tiny memset) + W prep ----
    hipMemsetAsync(bktcnt, 0, MAXNC * 4, stream);
    scatter_bkt<<<B1 + 2, 512, 0, stream>>>(src, dst, bktcnt, slack, E, NC, chunk,
                                            W1, W2, w1h, w1l, w2h, w2l);
    build_csr2<<<NC, 256, 0, stream>>>(bktcnt, slack, row_off, disqrt, col, NC, N);

    // ---- layer 1 ----
    gemm_mfma<IN_DIM, true><<<(N + 127) / 128, 256, 0, stream>>>(
        x, w1h, w1l, disqrt, Tsb, N);
    agg_kernel<false><<<(N + 3) / 4, 256, 0, stream>>>(Tsb, row_off, col, disqrt,
                                                       b1, nullptr, nullptr,
                                                       h1b, nullptr, 0, N);

    // ---- layer 2 + fused fc ----
    gemm_mfma<HID, false><<<(N + 127) / 128, 256, 0, stream>>>(
        h1b, w2h, w2l, disqrt, Tsb, N);
    agg_kernel<true><<<(N + 3) / 4, 256, 0, stream>>>(Tsb, row_off, col, disqrt,
                                                      b2, Wfc, bfc,
                                                      nullptr, out, 0, N);
}